// Round 1
// baseline (168.439 us; speedup 1.0000x reference)
//
#include <hip/hip_runtime.h>
#include <hip/hip_bf16.h>
#include <stdint.h>

#define SEQ   4096
#define DM    128
#define KVB   64

typedef __attribute__((ext_vector_type(8)))  short  bf16x8;
typedef __attribute__((ext_vector_type(16))) float  f32x16;

// (1/sqrt(128)) * log2(e): folded into Wq so logits are already in exp2 domain
#define SCALE_LOG2E 0.12751743f

__device__ __forceinline__ f32x16 mfma_32x32x16(bf16x8 a, bf16x8 b, f32x16 c) {
  return __builtin_amdgcn_mfma_f32_32x32x16_bf16(a, b, c, 0, 0, 0);
}

__device__ __forceinline__ void gload16(const void* g, void* l) {
  __builtin_amdgcn_global_load_lds(
      (const __attribute__((address_space(1))) unsigned int*)g,
      (__attribute__((address_space(3))) unsigned int*)l, 16, 0, 0);
}

__device__ __forceinline__ unsigned pack2bf(float a, float b) {
  float2 t; t.x = a; t.y = b;
  __hip_bfloat162 h = __float22bfloat162_rn(t);
  union { __hip_bfloat162 h2; unsigned u; } cv;
  cv.h2 = h;
  return cv.u;
}

__device__ __forceinline__ float fast_exp2(float x) {
#if defined(__has_builtin)
#if __has_builtin(__builtin_amdgcn_exp2f)
  return __builtin_amdgcn_exp2f(x);
#else
  return exp2f(x);
#endif
#else
  return exp2f(x);
#endif
}

// ---------------------------------------------------------------------------
// Kernel 0: repack weights fp32 -> bf16 in MFMA B-fragment order.
// Layout: Wb[ct][s][lane][i], ct in [0,12) (Q:0-3, K:4-7, V:8-11 col-tiles of 32),
// s = k-step (K=16 each, 8 steps over D=128), lane's frag elem i -> d = 16s+8*(lane>>5)+i,
// h = (ct&3)*32 + (lane&31).  Wq gets scale*log2e folded in.
// ---------------------------------------------------------------------------
__global__ void prep_w(const float* __restrict__ Wq, const float* __restrict__ Wk,
                       const float* __restrict__ Wv, __hip_bfloat16* __restrict__ Wb) {
  int t = blockIdx.x * 256 + threadIdx.x;
  if (t >= 12 * 8 * 64) return;
  int ct  = t >> 9;
  int rem = t & 511;
  int s   = rem >> 6;
  int l   = rem & 63;
  const float* W = (ct < 4) ? Wq : (ct < 8) ? Wk : Wv;
  float c = (ct < 4) ? SCALE_LOG2E : 1.0f;
  int h  = (ct & 3) * 32 + (l & 31);
  int d0 = 16 * s + 8 * (l >> 5);
  union { __hip_bfloat16 h8[8]; bf16x8 v; } u;
#pragma unroll
  for (int i = 0; i < 8; ++i) u.h8[i] = __float2bfloat16(W[(d0 + i) * DM + h] * c);
  *(bf16x8*)&Wb[(size_t)t * 8] = u.v;
}

// ---------------------------------------------------------------------------
// Kernel 1: QKV projection.  512 blocks x 256 thr; wave owns 32 token rows.
// q_ws/k_ws: [B*L][128] bf16 row-major.  vT_ws: [B][128][4096] bf16 (transposed!)
// so attention can stage V^T tiles row-major.
// ---------------------------------------------------------------------------
__global__ void __launch_bounds__(256, 2)
proj(const float* __restrict__ x, const __hip_bfloat16* __restrict__ Wb,
     __hip_bfloat16* __restrict__ qw, __hip_bfloat16* __restrict__ kw,
     __hip_bfloat16* __restrict__ vtw) {
  __shared__ __hip_bfloat16 slab[4][1024];  // per-wave 32x32 bounce tile
  const int wave = threadIdx.x >> 6, lane = threadIdx.x & 63;
  const int l31 = lane & 31, hi = lane >> 5;
  const int t0 = blockIdx.x * 128 + wave * 32;
  const int trow = t0 + l31;

  // A-fragments: x rows fp32 -> bf16, lane: row=l31, d = 16s+8hi+i
  bf16x8 af[8];
#pragma unroll
  for (int s = 0; s < 8; ++s) {
    const float* px = x + (size_t)trow * DM + 16 * s + 8 * hi;
    float4 u0 = *(const float4*)px;
    float4 u1 = *(const float4*)(px + 4);
    union { bf16x8 v; unsigned u[4]; } fr;
    fr.u[0] = pack2bf(u0.x, u0.y);
    fr.u[1] = pack2bf(u0.z, u0.w);
    fr.u[2] = pack2bf(u1.x, u1.y);
    fr.u[3] = pack2bf(u1.z, u1.w);
    af[s] = fr.v;
  }

  for (int ct = 0; ct < 12; ++ct) {
    f32x16 acc;
#pragma unroll
    for (int j = 0; j < 16; ++j) acc[j] = 0.f;
#pragma unroll
    for (int s = 0; s < 8; ++s) {
      bf16x8 bfr = *(const bf16x8*)&Wb[(size_t)((ct * 8 + s) * 64 + lane) * 8];
      acc = mfma_32x32x16(af[s], bfr, acc);
    }
    __syncthreads();  // previous iteration's slab reads done
    // C/D layout: col = lane&31, row = (j&3) + 8*(j>>2) + 4*hi   [m74/m101]
#pragma unroll
    for (int j = 0; j < 16; ++j) {
      int r = (j & 3) + 8 * (j >> 2) + 4 * hi;
      slab[wave][r * 32 + l31] = __float2bfloat16(acc[j]);
    }
    __syncthreads();
    if (ct < 8) {  // Q or K: row-major coalesced copy-out
      __hip_bfloat16* dst = (ct < 4) ? qw : kw;
      int hb = (ct & 3) * 32;
#pragma unroll
      for (int p = 0; p < 2; ++p) {
        int eidx = p * 512 + lane * 8;
        int tr = eidx >> 5, c = eidx & 31;
        *(bf16x8*)&dst[(size_t)(t0 + tr) * DM + hb + c] =
            *(const bf16x8*)&slab[wave][eidx];
      }
    } else {  // V: transposed copy-out, vT[b][d][t]
      int d  = lane >> 1;
      int th = (lane & 1) * 16;
      int dg = (ct & 3) * 32 + d;
      int bb = t0 >> 12;       // batch
      int tl = t0 & 4095;      // token within batch
      __hip_bfloat16* dst = vtw + ((size_t)bb * DM + dg) * SEQ + tl + th;
#pragma unroll
      for (int k = 0; k < 4; ++k) {
        union { unsigned short u4[4]; uint2 v; } pkv;
#pragma unroll
        for (int e = 0; e < 4; ++e) {
          union { __hip_bfloat16 hh; unsigned short us; } cv;
          cv.hh = slab[wave][(th + 4 * k + e) * 32 + d];
          pkv.u4[e] = cv.us;
        }
        *(uint2*)&dst[4 * k] = pkv.v;  // 8B store, contiguous in t
      }
    }
  }
}

// ---------------------------------------------------------------------------
// Kernel 2: causal flash attention.  512 blocks x 4 waves; wave owns 32 q rows
// (QBLK=128/block), KVBLK=64 staged in LDS (K tile [64][128], V^T tile [128][64],
// both XOR-swizzled byte^=(row&7)<<4 via pre-swizzled global_load_lds source).
// Swapped QK^T: S^T = mfma(K, Q) -> lane holds one q-row's P values in regs.
// ---------------------------------------------------------------------------
__global__ void __launch_bounds__(256, 2)
attn(const __hip_bfloat16* __restrict__ qw, const __hip_bfloat16* __restrict__ kw,
     const __hip_bfloat16* __restrict__ vtw, float* __restrict__ out) {
  __shared__ __align__(16) char lds[32768];  // [0,16K): K tile, [16K,32K): V^T tile
  const int bid = blockIdx.x;
  // causal load balance: bid and bid+256 (likely co-resident) get tiles pp, 31-pp
  const int half = bid >> 8;
  const int r8 = bid & 255;
  const int b  = r8 & 15;
  const int pp = r8 >> 4;
  const int qt = half ? (31 - pp) : pp;
  const int q0 = qt << 7;
  const int wave = threadIdx.x >> 6, lane = threadIdx.x & 63;
  const int l31 = lane & 31, hi = lane >> 5;
  const int qrow = q0 + wave * 32 + l31;  // this lane's q row (within batch)
  const int tid = threadIdx.x;

  // Q fragments hoisted to registers: B-operand of mfma(K,Q)
  bf16x8 qf[8];
  {
    const __hip_bfloat16* qb = qw + ((size_t)b * SEQ + qrow) * DM;
#pragma unroll
    for (int s = 0; s < 8; ++s) qf[s] = *(const bf16x8*)&qb[16 * s + 8 * hi];
  }
  f32x16 yacc[4];
#pragma unroll
  for (int dt = 0; dt < 4; ++dt)
#pragma unroll
    for (int j = 0; j < 16; ++j) yacc[dt][j] = 0.f;

  float mrun = -1e30f, lsum = 0.f;
  const int nkv = 2 * qt + 2;
  const int qminw = q0 + wave * 32;
  const int qmaxw = qminw + 31;
  const char* kb = (const char*)(kw + (size_t)b * SEQ * DM);
  const char* vb = (const char*)(vtw + (size_t)b * DM * SEQ);

  for (int t = 0; t < nkv; ++t) {
    const int kv0 = t * KVB;
    {  // stage K (16KB) + V^T (16KB); dest linear, source pre-swizzled
      const char* ksrc = kb + (size_t)kv0 * 256;
#pragma unroll
      for (int p = 0; p < 4; ++p) {
        int lin = p * 4096 + tid * 16;
        int row = lin >> 8, cb = lin & 255;
        int so = row * 256 + (cb ^ ((row & 7) << 4));
        gload16(ksrc + so, &lds[p * 4096 + (wave << 10)]);
      }
      const char* vsrc = vb + (size_t)kv0 * 2;
#pragma unroll
      for (int p = 0; p < 4; ++p) {
        int lin = p * 4096 + tid * 16;
        int row = lin >> 7, cb = lin & 127;
        int so = row * 8192 + (cb ^ ((row & 7) << 4));
        gload16(vsrc + so, &lds[16384 + p * 4096 + (wave << 10)]);
      }
    }
    __syncthreads();
    if (kv0 <= qmaxw) {  // wave-uniform causal skip
      // S^T = K @ Q^T for 2 key-subtiles of 32
      f32x16 sa, sb;
#pragma unroll
      for (int j = 0; j < 16; ++j) { sa[j] = 0.f; sb[j] = 0.f; }
#pragma unroll
      for (int s = 0; s < 8; ++s) {
        int cbs = 32 * s + 16 * hi;
        int r0 = l31, r1 = l31 + 32;
        bf16x8 k0 = *(const bf16x8*)&lds[r0 * 256 + (cbs ^ ((r0 & 7) << 4))];
        bf16x8 k1 = *(const bf16x8*)&lds[r1 * 256 + (cbs ^ ((r1 & 7) << 4))];
        sa = mfma_32x32x16(k0, qf[s], sa);
        sb = mfma_32x32x16(k1, qf[s], sb);
      }
      // causal mask (diagonal tiles only); key row = (j&3)+8*(j>>2)+4*hi
      if (kv0 + 63 > qminw) {
#pragma unroll
        for (int j = 0; j < 16; ++j) {
          int rr = (j & 3) + 8 * (j >> 2) + 4 * hi;
          sa[j] = (kv0 + rr      > qrow) ? -1e30f : sa[j];
          sb[j] = (kv0 + 32 + rr > qrow) ? -1e30f : sb[j];
        }
      }
      // online softmax in exp2 domain (scale*log2e folded into Q)
      float pmax = -1e30f;
#pragma unroll
      for (int j = 0; j < 16; ++j) pmax = fmaxf(pmax, fmaxf(sa[j], sb[j]));
      pmax = fmaxf(pmax, __shfl_xor(pmax, 32));
      float mn = fmaxf(mrun, pmax);
      float fs = fast_exp2(mrun - mn);
      mrun = mn;
      float ps = 0.f;
#pragma unroll
      for (int j = 0; j < 16; ++j) { sa[j] = fast_exp2(sa[j] - mn); ps += sa[j]; }
#pragma unroll
      for (int j = 0; j < 16; ++j) { sb[j] = fast_exp2(sb[j] - mn); ps += sb[j]; }
      ps += __shfl_xor(ps, 32);
      lsum = lsum * fs + ps;
#pragma unroll
      for (int dt = 0; dt < 4; ++dt)
#pragma unroll
        for (int j = 0; j < 16; ++j) yacc[dt][j] *= fs;

      // PV: Y^T += V^T @ P^T per key-subtile
#pragma unroll
      for (int a = 0; a < 2; ++a) {
        unsigned pk[8], xk[8];
#pragma unroll
        for (int jj = 0; jj < 8; ++jj) {
          float lo  = a ? sb[2 * jj]     : sa[2 * jj];
          float hi2 = a ? sb[2 * jj + 1] : sa[2 * jj + 1];
          pk[jj] = pack2bf(lo, hi2);  // keys 8*(jj>>1)+4hi+2*(jj&1)+{0,1}
        }
#pragma unroll
        for (int jj = 0; jj < 8; ++jj)
          xk[jj] = (unsigned)__shfl_xor((int)pk[jj], 32);
#pragma unroll
        for (int s2 = 0; s2 < 2; ++s2) {
          union { bf16x8 v; unsigned u[4]; } pf;  // B-frag: k=8hi+i, col=q
          int base = 4 * s2;
          pf.u[0] = hi ? xk[base + 2] : pk[base];
          pf.u[1] = hi ? xk[base + 3] : pk[base + 1];
          pf.u[2] = hi ? pk[base + 2] : xk[base];
          pf.u[3] = hi ? pk[base + 3] : xk[base + 1];
          int cbv = 64 * a + 32 * s2 + 16 * hi;
#pragma unroll
          for (int dt = 0; dt < 4; ++dt) {
            int rv = l31 + 32 * dt;
            bf16x8 vf = *(const bf16x8*)&lds[16384 + rv * 128 + (cbv ^ ((rv & 7) << 4))];
            yacc[dt] = mfma_32x32x16(vf, pf.v, yacc[dt]);
          }
        }
      }
    }
    __syncthreads();
  }

  // epilogue: y = Y^T / lsum; lane owns q-col, regs give 4 consecutive d -> float4
  float inv = 1.0f / lsum;
  float* ob = out + ((size_t)b * SEQ + qrow) * DM;
#pragma unroll
  for (int dt = 0; dt < 4; ++dt) {
#pragma unroll
    for (int g = 0; g < 4; ++g) {
      float4 v;
      v.x = yacc[dt][4 * g + 0] * inv;
      v.y = yacc[dt][4 * g + 1] * inv;
      v.z = yacc[dt][4 * g + 2] * inv;
      v.w = yacc[dt][4 * g + 3] * inv;
      *(float4*)&ob[32 * dt + 8 * g + 4 * hi] = v;
    }
  }
}

extern "C" void kernel_launch(void* const* d_in, const int* in_sizes, int n_in,
                              void* d_out, int out_size, void* d_ws, size_t ws_size,
                              hipStream_t stream) {
  const float* x  = (const float*)d_in[0];
  const float* Wq = (const float*)d_in[1];
  const float* Wk = (const float*)d_in[2];
  const float* Wv = (const float*)d_in[3];
  float* out = (float*)d_out;

  char* ws = (char*)d_ws;
  __hip_bfloat16* qw  = (__hip_bfloat16*)(ws);                              // 16 MB
  __hip_bfloat16* kw  = (__hip_bfloat16*)(ws + (size_t)16 * 1024 * 1024);   // 16 MB
  __hip_bfloat16* vtw = (__hip_bfloat16*)(ws + (size_t)32 * 1024 * 1024);   // 16 MB
  __hip_bfloat16* Wb  = (__hip_bfloat16*)(ws + (size_t)48 * 1024 * 1024);   // 96 KB

  prep_w<<<24, 256, 0, stream>>>(Wq, Wk, Wv, Wb);
  proj<<<512, 256, 0, stream>>>(x, Wb, qw, kw, vtw);
  attn<<<512, 256, 0, stream>>>(qw, kw, vtw, out);
}

// Round 2
// 148.974 us; speedup vs baseline: 1.1307x; 1.1307x over previous
//
#include <hip/hip_runtime.h>
#include <hip/hip_bf16.h>
#include <stdint.h>

#define SEQ   4096
#define DM    128
#define KVB   64

typedef __attribute__((ext_vector_type(8)))  short  bf16x8;
typedef __attribute__((ext_vector_type(16))) float  f32x16;

// (1/sqrt(128)) * log2(e): folded into Wq so logits are already in exp2 domain
#define SCALE_LOG2E 0.12751743f

__device__ __forceinline__ f32x16 mfma_32x32x16(bf16x8 a, bf16x8 b, f32x16 c) {
  return __builtin_amdgcn_mfma_f32_32x32x16_bf16(a, b, c, 0, 0, 0);
}

__device__ __forceinline__ void gload16(const void* g, void* l) {
  __builtin_amdgcn_global_load_lds(
      (const __attribute__((address_space(1))) unsigned int*)g,
      (__attribute__((address_space(3))) unsigned int*)l, 16, 0, 0);
}

__device__ __forceinline__ unsigned pack2bf(float a, float b) {
  float2 t; t.x = a; t.y = b;
  __hip_bfloat162 h = __float22bfloat162_rn(t);
  union { __hip_bfloat162 h2; unsigned u; } cv;
  cv.h2 = h;
  return cv.u;
}

__device__ __forceinline__ float fast_exp2(float x) {
#if defined(__has_builtin)
#if __has_builtin(__builtin_amdgcn_exp2f)
  return __builtin_amdgcn_exp2f(x);
#else
  return exp2f(x);
#endif
#else
  return exp2f(x);
#endif
}

// ---------------------------------------------------------------------------
// Kernel 0: repack weights fp32 -> bf16 in MFMA B-fragment order.
// ---------------------------------------------------------------------------
__global__ void prep_w(const float* __restrict__ Wq, const float* __restrict__ Wk,
                       const float* __restrict__ Wv, __hip_bfloat16* __restrict__ Wb) {
  int t = blockIdx.x * 256 + threadIdx.x;
  if (t >= 12 * 8 * 64) return;
  int ct  = t >> 9;
  int rem = t & 511;
  int s   = rem >> 6;
  int l   = rem & 63;
  const float* W = (ct < 4) ? Wq : (ct < 8) ? Wk : Wv;
  float c = (ct < 4) ? SCALE_LOG2E : 1.0f;
  int h  = (ct & 3) * 32 + (l & 31);
  int d0 = 16 * s + 8 * (l >> 5);
  union { __hip_bfloat16 h8[8]; bf16x8 v; } u;
#pragma unroll
  for (int i = 0; i < 8; ++i) u.h8[i] = __float2bfloat16(W[(d0 + i) * DM + h] * c);
  *(bf16x8*)&Wb[(size_t)t * 8] = u.v;
}

// ---------------------------------------------------------------------------
// Kernel 1: QKV projection (unchanged from R0; ~10 us, not the bottleneck).
// ---------------------------------------------------------------------------
__global__ void __launch_bounds__(256, 2)
proj(const float* __restrict__ x, const __hip_bfloat16* __restrict__ Wb,
     __hip_bfloat16* __restrict__ qw, __hip_bfloat16* __restrict__ kw,
     __hip_bfloat16* __restrict__ vtw) {
  __shared__ __hip_bfloat16 slab[4][1024];
  const int wave = threadIdx.x >> 6, lane = threadIdx.x & 63;
  const int l31 = lane & 31, hi = lane >> 5;
  const int t0 = blockIdx.x * 128 + wave * 32;
  const int trow = t0 + l31;

  bf16x8 af[8];
#pragma unroll
  for (int s = 0; s < 8; ++s) {
    const float* px = x + (size_t)trow * DM + 16 * s + 8 * hi;
    float4 u0 = *(const float4*)px;
    float4 u1 = *(const float4*)(px + 4);
    union { bf16x8 v; unsigned u[4]; } fr;
    fr.u[0] = pack2bf(u0.x, u0.y);
    fr.u[1] = pack2bf(u0.z, u0.w);
    fr.u[2] = pack2bf(u1.x, u1.y);
    fr.u[3] = pack2bf(u1.z, u1.w);
    af[s] = fr.v;
  }

  for (int ct = 0; ct < 12; ++ct) {
    f32x16 acc;
#pragma unroll
    for (int j = 0; j < 16; ++j) acc[j] = 0.f;
#pragma unroll
    for (int s = 0; s < 8; ++s) {
      bf16x8 bfr = *(const bf16x8*)&Wb[(size_t)((ct * 8 + s) * 64 + lane) * 8];
      acc = mfma_32x32x16(af[s], bfr, acc);
    }
    __syncthreads();
#pragma unroll
    for (int j = 0; j < 16; ++j) {
      int r = (j & 3) + 8 * (j >> 2) + 4 * hi;
      slab[wave][r * 32 + l31] = __float2bfloat16(acc[j]);
    }
    __syncthreads();
    if (ct < 8) {
      __hip_bfloat16* dst = (ct < 4) ? qw : kw;
      int hb = (ct & 3) * 32;
#pragma unroll
      for (int p = 0; p < 2; ++p) {
        int eidx = p * 512 + lane * 8;
        int tr = eidx >> 5, c = eidx & 31;
        *(bf16x8*)&dst[(size_t)(t0 + tr) * DM + hb + c] =
            *(const bf16x8*)&slab[wave][eidx];
      }
    } else {
      int d  = lane >> 1;
      int th = (lane & 1) * 16;
      int dg = (ct & 3) * 32 + d;
      int bb = t0 >> 12;
      int tl = t0 & 4095;
      __hip_bfloat16* dst = vtw + ((size_t)bb * DM + dg) * SEQ + tl + th;
#pragma unroll
      for (int k = 0; k < 4; ++k) {
        union { unsigned short u4[4]; uint2 v; } pkv;
#pragma unroll
        for (int e = 0; e < 4; ++e) {
          union { __hip_bfloat16 hh; unsigned short us; } cv;
          cv.hh = slab[wave][(th + 4 * k + e) * 32 + d];
          pkv.u4[e] = cv.us;
        }
        *(uint2*)&dst[4 * k] = pkv.v;
      }
    }
  }
}

// ---------------------------------------------------------------------------
// Kernel 2: causal flash attention, double-buffered prefetch (2-phase).
// Per iter: issue next tile's global_load_lds -> compute current -> one barrier
// (compiler's vmcnt(0) drain there waits on loads that flew during compute).
// K tile [64][256B] swizzled byte^=(row&15)<<4 (16-slot, conflict-free);
// V^T tile [128][128B] swizzled byte^=(row&7)<<4.
// ---------------------------------------------------------------------------
__device__ __forceinline__ void stage_kv(const char* kb, const char* vb, int kv0,
                                         char* dst, int tid, int wave) {
  const char* ksrc = kb + (size_t)kv0 * 256;
#pragma unroll
  for (int p = 0; p < 4; ++p) {
    int lin = p * 4096 + tid * 16;
    int row = lin >> 8, cb = lin & 255;
    int so = row * 256 + (cb ^ ((row & 15) << 4));
    gload16(ksrc + so, dst + p * 4096 + (wave << 10));
  }
  const char* vsrc = vb + (size_t)kv0 * 2;
#pragma unroll
  for (int p = 0; p < 4; ++p) {
    int lin = p * 4096 + tid * 16;
    int row = lin >> 7, cb = lin & 127;
    size_t so = (size_t)row * 8192 + (size_t)(cb ^ ((row & 7) << 4));
    gload16(vsrc + so, dst + 16384 + p * 4096 + (wave << 10));
  }
}

__global__ void __launch_bounds__(256, 2)
attn(const __hip_bfloat16* __restrict__ qw, const __hip_bfloat16* __restrict__ kw,
     const __hip_bfloat16* __restrict__ vtw, float* __restrict__ out) {
  __shared__ __align__(16) char lds[65536];  // 2 x (16KB K + 16KB V^T)
  const int bid = blockIdx.x;
  const int half = bid >> 8;
  const int r8 = bid & 255;
  const int b  = r8 & 15;
  const int pp = r8 >> 4;
  const int qt = half ? (31 - pp) : pp;
  const int q0 = qt << 7;
  const int wave = threadIdx.x >> 6, lane = threadIdx.x & 63;
  const int l31 = lane & 31, hi = lane >> 5;
  const int qrow = q0 + wave * 32 + l31;
  const int tid = threadIdx.x;

  bf16x8 qf[8];
  {
    const __hip_bfloat16* qb = qw + ((size_t)b * SEQ + qrow) * DM;
#pragma unroll
    for (int s = 0; s < 8; ++s) qf[s] = *(const bf16x8*)&qb[16 * s + 8 * hi];
  }
  f32x16 yacc[4];
#pragma unroll
  for (int dt = 0; dt < 4; ++dt)
#pragma unroll
    for (int j = 0; j < 16; ++j) yacc[dt][j] = 0.f;

  float mrun = -1e30f, lsum = 0.f;
  const int nkv = 2 * qt + 2;
  const int qmaxw = q0 + wave * 32 + 31;
  const char* kb = (const char*)(kw + (size_t)b * SEQ * DM);
  const char* vb = (const char*)(vtw + (size_t)b * DM * SEQ);

  stage_kv(kb, vb, 0, lds, tid, wave);
  __syncthreads();

  for (int t = 0; t < nkv; ++t) {
    char* cur = lds + ((t & 1) << 15);
    if (t + 1 < nkv)
      stage_kv(kb, vb, (t + 1) * KVB, lds + (((t + 1) & 1) << 15), tid, wave);

    const int kv0 = t * KVB;
    if (kv0 <= qmaxw) {
      // S^T = K @ Q^T for 2 key-subtiles of 32
      f32x16 sa, sb;
#pragma unroll
      for (int j = 0; j < 16; ++j) { sa[j] = 0.f; sb[j] = 0.f; }
#pragma unroll
      for (int s = 0; s < 8; ++s) {
        int cbs = 32 * s + 16 * hi;
        int r0 = l31, r1 = l31 + 32;
        bf16x8 k0 = *(const bf16x8*)&cur[r0 * 256 + (cbs ^ ((r0 & 15) << 4))];
        bf16x8 k1 = *(const bf16x8*)&cur[r1 * 256 + (cbs ^ ((r1 & 15) << 4))];
        sa = mfma_32x32x16(k0, qf[s], sa);
        sb = mfma_32x32x16(k1, qf[s], sb);
      }
      // causal mask (diagonal tiles only); key row = (j&3)+8*(j>>2)+4*hi
      if (kv0 + 63 > q0 + wave * 32) {
#pragma unroll
        for (int j = 0; j < 16; ++j) {
          int rr = (j & 3) + 8 * (j >> 2) + 4 * hi;
          sa[j] = (kv0 + rr      > qrow) ? -1e30f : sa[j];
          sb[j] = (kv0 + 32 + rr > qrow) ? -1e30f : sb[j];
        }
      }
      // online softmax, exp2 domain, defer-max (THR=8 -> P <= 256, f32-safe)
      float pmax = -1e30f;
#pragma unroll
      for (int j = 0; j < 16; ++j) pmax = fmaxf(pmax, fmaxf(sa[j], sb[j]));
      pmax = fmaxf(pmax, __shfl_xor(pmax, 32));
      if (!__all(pmax - mrun <= 8.0f)) {
        float mn = fmaxf(mrun, pmax);
        float fs = fast_exp2(mrun - mn);
        mrun = mn;
        lsum *= fs;
#pragma unroll
        for (int dt = 0; dt < 4; ++dt)
#pragma unroll
          for (int j = 0; j < 16; ++j) yacc[dt][j] *= fs;
      }
      float ps = 0.f;
#pragma unroll
      for (int j = 0; j < 16; ++j) { sa[j] = fast_exp2(sa[j] - mrun); ps += sa[j]; }
#pragma unroll
      for (int j = 0; j < 16; ++j) { sb[j] = fast_exp2(sb[j] - mrun); ps += sb[j]; }
      ps += __shfl_xor(ps, 32);
      lsum += ps;

      // PV: Y^T += V^T @ P^T per key-subtile (pre-select halves -> 2 shfl per s2)
#pragma unroll
      for (int a = 0; a < 2; ++a) {
        unsigned pk[8];
#pragma unroll
        for (int jj = 0; jj < 8; ++jj) {
          float lo  = a ? sb[2 * jj]     : sa[2 * jj];
          float hi2 = a ? sb[2 * jj + 1] : sa[2 * jj + 1];
          pk[jj] = pack2bf(lo, hi2);
        }
#pragma unroll
        for (int s2 = 0; s2 < 2; ++s2) {
          int base = 4 * s2;
          unsigned send0 = hi ? pk[base]     : pk[base + 2];
          unsigned send1 = hi ? pk[base + 1] : pk[base + 3];
          unsigned r0 = (unsigned)__shfl_xor((int)send0, 32);
          unsigned r1 = (unsigned)__shfl_xor((int)send1, 32);
          union { bf16x8 v; unsigned u[4]; } pf;
          pf.u[0] = hi ? r0 : pk[base];
          pf.u[1] = hi ? r1 : pk[base + 1];
          pf.u[2] = hi ? pk[base + 2] : r0;
          pf.u[3] = hi ? pk[base + 3] : r1;
          int cbv = 64 * a + 32 * s2 + 16 * hi;
#pragma unroll
          for (int dt = 0; dt < 4; ++dt) {
            int rv = l31 + 32 * dt;
            bf16x8 vf = *(const bf16x8*)&cur[16384 + rv * 128 + (cbv ^ ((rv & 7) << 4))];
            yacc[dt] = mfma_32x32x16(vf, pf.v, yacc[dt]);
          }
        }
      }
    }
    __syncthreads();
  }

  float inv = 1.0f / lsum;
  float* ob = out + ((size_t)b * SEQ + qrow) * DM;
#pragma unroll
  for (int dt = 0; dt < 4; ++dt) {
#pragma unroll
    for (int g = 0; g < 4; ++g) {
      float4 v;
      v.x = yacc[dt][4 * g + 0] * inv;
      v.y = yacc[dt][4 * g + 1] * inv;
      v.z = yacc[dt][4 * g + 2] * inv;
      v.w = yacc[dt][4 * g + 3] * inv;
      *(float4*)&ob[32 * dt + 8 * g + 4 * hi] = v;
    }
  }
}

extern "C" void kernel_launch(void* const* d_in, const int* in_sizes, int n_in,
                              void* d_out, int out_size, void* d_ws, size_t ws_size,
                              hipStream_t stream) {
  const float* x  = (const float*)d_in[0];
  const float* Wq = (const float*)d_in[1];
  const float* Wk = (const float*)d_in[2];
  const float* Wv = (const float*)d_in[3];
  float* out = (float*)d_out;

  char* ws = (char*)d_ws;
  __hip_bfloat16* qw  = (__hip_bfloat16*)(ws);
  __hip_bfloat16* kw  = (__hip_bfloat16*)(ws + (size_t)16 * 1024 * 1024);
  __hip_bfloat16* vtw = (__hip_bfloat16*)(ws + (size_t)32 * 1024 * 1024);
  __hip_bfloat16* Wb  = (__hip_bfloat16*)(ws + (size_t)48 * 1024 * 1024);

  prep_w<<<24, 256, 0, stream>>>(Wq, Wk, Wv, Wb);
  proj<<<512, 256, 0, stream>>>(x, Wb, qw, kw, vtw);
  attn<<<512, 256, 0, stream>>>(qw, kw, vtw, out);
}